// Round 20
// baseline (365.061 us; speedup 1.0000x reference)
//
#include <hip/hip_runtime.h>
#include <hip/hip_bf16.h>
#include <math.h>

typedef short bf16x8 __attribute__((ext_vector_type(8)));
typedef float f32x4 __attribute__((ext_vector_type(4)));

#define LN_EPS 1e-5f

static __device__ __forceinline__ float b2f(unsigned short u){
  unsigned int x = ((unsigned int)u) << 16; float f; __builtin_memcpy(&f,&x,4); return f;
}
static __device__ __forceinline__ unsigned short f2b(float f){
  unsigned int x; __builtin_memcpy(&x,&f,4);
  x += 0x7fffu + ((x>>16)&1u);   // RNE
  return (unsigned short)(x>>16);
}

// async global->LDS, 16B per lane; LDS dest = uniform base + lane*16
static __device__ __forceinline__ void gload_lds16(const void* g, void* l){
  __builtin_amdgcn_global_load_lds(
      (const __attribute__((address_space(1))) unsigned int*)g,
      (__attribute__((address_space(3))) unsigned int*)l, 16, 0, 0);
}

#define MFMA16(a,b,c) __builtin_amdgcn_mfma_f32_16x16x32_bf16(a,b,c,0,0,0)

// ---------- fused weight packs: Wc (3136x149 -> 3200x160 pad) + Wq copy + Wk copy
// flat ranges: [0, 512000) Wc, [512000, 905216) Wq (512x768), [905216, 1167360) Wk (512x512)
__global__ void pack_weights(const float* __restrict__ Wc, const float* __restrict__ Wq,
                             const float* __restrict__ Wk, unsigned short* __restrict__ WcB,
                             unsigned short* __restrict__ WqB, unsigned short* __restrict__ WkB){
  int idx = blockIdx.x*256 + threadIdx.x;
  if (idx < 512000){
    int r = idx / 160, kk = idx - r*160;
    float v = (r < 3136 && kk < 149) ? Wc[(size_t)r*149 + kk] : 0.f;
    WcB[idx] = f2b(v);
  } else if (idx < 905216){
    int i = idx - 512000;
    WqB[i] = f2b(Wq[i]);
  } else if (idx < 1167360){
    int i = idx - 905216;
    WkB[i] = f2b(Wk[i]);
  }
}

// ---------- x (B,149,768) f32 -> xt (B,768,160) bf16, zero pad l>=149
__global__ __launch_bounds__(256) void pack_xt(const float* __restrict__ x, unsigned short* __restrict__ xt){
  __shared__ float tile[32][33];
  int b = blockIdx.z;
  int l0 = blockIdx.y*32, d0 = blockIdx.x*32;
  int tl = threadIdx.x & 31, tw = threadIdx.x >> 5;
  for (int r=0;r<32;r+=8){
    int l = l0 + tw + r;
    tile[tw+r][tl] = (l<149) ? x[((size_t)b*149 + l)*768 + d0 + tl] : 0.f;
  }
  __syncthreads();
  for (int r=0;r<32;r+=8){
    int d = d0 + tw + r;
    int l = l0 + tl;
    if (l < 160) xt[((size_t)b*768 + d)*160 + l] = f2b(tile[tl][tw+r]);
  }
}

// ---------- pe (C,3136) f32 -> (3136,C) f32   (used for pe_wave only)
__global__ __launch_bounds__(256) void transpose_pe(const float* __restrict__ src, float* __restrict__ dst, int C){
  __shared__ float tile[32][33];
  int c0 = blockIdx.y*32, o0 = blockIdx.x*32;
  int tl = threadIdx.x & 31, tw = threadIdx.x >> 5;
  for (int r=0;r<32;r+=8)
    tile[tw+r][tl] = src[(size_t)(c0+tw+r)*3136 + o0 + tl];
  __syncthreads();
  for (int r=0;r<32;r+=8)
    dst[(size_t)(o0+tw+r)*C + c0 + tl] = tile[tl][tw+r];
}

// ---------- conv1d GEMM, K=160 single-shot: 128x128 tile, whole K in LDS (80 KB),
// ONE barrier per block, 2 blocks/CU. C[m][n] = sum_k A[m][k]*Bt[n][k].
__global__ __launch_bounds__(256)
void conv160(const unsigned short* __restrict__ A, const unsigned short* __restrict__ Bt,
             unsigned short* __restrict__ C, int M, int N,
             long long bStride, long long cStride){
  __shared__ __align__(16) unsigned short lds[40960];  // A 128x160 + B 128x160 (81920 B)
  const int K = 160;
  int tid = threadIdx.x;
  int lane = tid & 63, wave = tid >> 6;
  int wm = (wave >> 1)*64, wn = (wave & 1)*64;
  int lr = lane & 15, lo = lane >> 4;
  int m0 = blockIdx.x*128, n0 = blockIdx.y*128;
  const unsigned short* Bb = Bt + (size_t)blockIdx.z*bStride;
  unsigned short* Cb = C + (size_t)blockIdx.z*cStride;

  #pragma unroll
  for (int i=0;i<20;i++){
    int cbase = i*256 + wave*64;           // uniform per instruction
    int tensor = (cbase >= 2560) ? 1 : 0;
    int ccb = cbase - tensor*2560;
    int cc = ccb + lane;
    int r = cc / 20, pc = cc - r*20;
    int sw = (r ^ (r >> 2)) & 3;
    int ps = pc ^ sw;                       // XOR low 2 bits only; 20 = 5 groups of 4
    const unsigned short* srcT = tensor ? (Bb + (size_t)n0*K) : (A + (size_t)m0*K);
    gload_lds16(srcT + (size_t)r*K + ps*8, lds + tensor*20480 + ccb*8);
  }
  asm volatile("s_waitcnt vmcnt(0)" ::: "memory");
  __builtin_amdgcn_s_barrier();

  f32x4 acc[4][4];
  #pragma unroll
  for (int i=0;i<4;i++)
    #pragma unroll
    for (int j=0;j<4;j++) acc[i][j]=(f32x4){0.f,0.f,0.f,0.f};
  #pragma unroll
  for (int kk=0; kk<5; ++kk){
    bf16x8 af[4], bfr[4];
    #pragma unroll
    for (int mi=0;mi<4;mi++){
      int row = wm + mi*16 + lr;
      int p = kk*4 + (lo ^ ((row ^ (row>>2)) & 3));
      af[mi] = *reinterpret_cast<const bf16x8*>(&lds[row*160 + p*8]);
    }
    #pragma unroll
    for (int nj=0;nj<4;nj++){
      int row = wn + nj*16 + lr;
      int p = kk*4 + (lo ^ ((row ^ (row>>2)) & 3));
      bfr[nj] = *reinterpret_cast<const bf16x8*>(&lds[20480 + row*160 + p*8]);
    }
    #pragma unroll
    for (int mi=0;mi<4;mi++)
      #pragma unroll
      for (int nj=0;nj<4;nj++)
        acc[mi][nj] = MFMA16(af[mi], bfr[nj], acc[mi][nj]);
  }
  int er = lo*4;
  #pragma unroll
  for (int mi=0;mi<4;mi++)
    #pragma unroll
    for (int nj=0;nj<4;nj++){
      int col = n0 + wn + nj*16 + lr;
      #pragma unroll
      for (int e=0;e<4;e++){
        int row = m0 + wm + mi*16 + er + e;
        if (row < M) Cb[(size_t)row*N + col] = f2b(acc[mi][nj][e]);
      }
    }
}

// ---------- merged Q+K 256x256 8-phase GEMM (T1..T5, fixed-boundary counted vmcnt).
// grid 784; parity interleave q_sel = sid&1. BK=64, conflict-free swizzle.
// NEW: through-LDS coalesced C epilogue (C tile = 128KB = exactly the LDS buffer).
__global__ __launch_bounds__(512)
void gemm256_dual(const unsigned short* __restrict__ A0, const unsigned short* __restrict__ Bt0,
                  unsigned short* __restrict__ C0, const float* __restrict__ bias0, int K0,
                  const unsigned short* __restrict__ A1, const unsigned short* __restrict__ Bt1,
                  unsigned short* __restrict__ C1, const float* __restrict__ bias1, int K1,
                  int M, int N){
  __shared__ __align__(16) unsigned short lds[65536];   // 131072 B
  int tid = threadIdx.x;
  int lane = tid & 63, wave = tid >> 6;
  int wr = wave >> 2, wc = wave & 3;
  int lr = lane & 15, lo = lane >> 4;
  int cpx = gridDim.x >> 3;
  int id = blockIdx.x;
  int sid = (id & 7)*cpx + (id >> 3);     // bijective XCD swizzle over 8 x cpx
  int q_sel = sid & 1;
  int s2 = sid >> 1;
  const unsigned short* A; const unsigned short* Bt; unsigned short* C;
  const float* bias; int K;
  if (q_sel == 0){ A=A0; Bt=Bt0; C=C0; bias=bias0; K=K0; }
  else           { A=A1; Bt=Bt1; C=C1; bias=bias1; K=K1; }
  int nby = N >> 8;                       // 2
  int bx = s2 / nby, by = s2 - bx*nby;
  int m0 = bx << 8, n0 = by << 8;
  int NT = K >> 6;

  f32x4 acc[8][4];
  #pragma unroll
  for (int i=0;i<8;i++)
    #pragma unroll
    for (int j=0;j<4;j++) acc[i][j]=(f32x4){0.f,0.f,0.f,0.f};

  auto STAGE = [&](int t, int h){   // h: 0=A_h0, 1=A_h1, 2=B_h0, 3=B_h1
    if (t >= NT) return;
    int buf = t & 1, tensor = h >> 1, hh = h & 1;
    int k0 = t << 6;
    unsigned short* dstbase = lds + buf*32768 + tensor*16384;
    const unsigned short* srcT = tensor ? (Bt + (size_t)n0*K) : (A + (size_t)m0*K);
    #pragma unroll
    for (int ldi=0; ldi<2; ldi++){
      int c = hh*1024 + ldi*512 + tid;
      int r = c >> 3;
      int l = (c & 7) ^ (r & 7);            // pre-swizzled source chunk
      gload_lds16(srcT + (size_t)r*K + k0 + l*8,
                  dstbase + (hh*1024 + ldi*512 + (wave<<6))*8);
    }
  };
  const char* ldsc = reinterpret_cast<const char*>(lds);
  int swz = lr & 7;
  auto rdA = [&](int buf, int mi, int kk)->bf16x8{
    int off = buf*65536 + (wr*128 + mi*16 + lr)*128 + (((kk*4+lo) ^ swz)*16);
    return *reinterpret_cast<const bf16x8*>(ldsc + off);
  };
  auto rdB = [&](int buf, int nj, int kk)->bf16x8{
    int off = buf*65536 + 32768 + (wc*64 + nj*16 + lr)*128 + (((kk*4+lo) ^ swz)*16);
    return *reinterpret_cast<const bf16x8*>(ldsc + off);
  };

  // prologue: tile0 fully + tile1 first half-tile; wait all but tile1:A_h0
  STAGE(0,0); STAGE(0,1); STAGE(0,2); STAGE(0,3); STAGE(1,0);
  asm volatile("s_waitcnt vmcnt(2)" ::: "memory");
  __builtin_amdgcn_s_barrier();

  for (int t=0; t<NT; ++t){
    int buf = t & 1;
    bf16x8 bf_[4][2], a0_[2][2], a1_[2][2];
    // ---- phase 0: B all + A q0,q1 ; stage (t+1,A_h1)
    #pragma unroll
    for (int nj=0;nj<4;nj++){ bf_[nj][0]=rdB(buf,nj,0); bf_[nj][1]=rdB(buf,nj,1); }
    #pragma unroll
    for (int i=0;i<2;i++){ a0_[i][0]=rdA(buf,i,0);   a0_[i][1]=rdA(buf,i,1); }
    #pragma unroll
    for (int i=0;i<2;i++){ a1_[i][0]=rdA(buf,2+i,0); a1_[i][1]=rdA(buf,2+i,1); }
    STAGE(t+1, 1);
    __builtin_amdgcn_s_barrier();
    asm volatile("s_waitcnt lgkmcnt(0)" ::: "memory");
    __builtin_amdgcn_sched_barrier(0);
    __builtin_amdgcn_s_setprio(1);
    #pragma unroll
    for (int i=0;i<2;i++)
      #pragma unroll
      for (int nj=0;nj<4;nj++){
        acc[i][nj] = MFMA16(a0_[i][0], bf_[nj][0], acc[i][nj]);
        acc[i][nj] = MFMA16(a0_[i][1], bf_[nj][1], acc[i][nj]);
      }
    __builtin_amdgcn_s_setprio(0);
    __builtin_amdgcn_s_barrier();
    // ---- phase 1: A q2 ; stage (t+1,B_h0)
    #pragma unroll
    for (int i=0;i<2;i++){ a0_[i][0]=rdA(buf,4+i,0); a0_[i][1]=rdA(buf,4+i,1); }
    STAGE(t+1, 2);
    __builtin_amdgcn_s_barrier();
    asm volatile("s_waitcnt lgkmcnt(0)" ::: "memory");
    __builtin_amdgcn_sched_barrier(0);
    __builtin_amdgcn_s_setprio(1);
    #pragma unroll
    for (int i=0;i<2;i++)
      #pragma unroll
      for (int nj=0;nj<4;nj++){
        acc[2+i][nj] = MFMA16(a1_[i][0], bf_[nj][0], acc[2+i][nj]);
        acc[2+i][nj] = MFMA16(a1_[i][1], bf_[nj][1], acc[2+i][nj]);
      }
    __builtin_amdgcn_s_setprio(0);
    __builtin_amdgcn_s_barrier();
    // ---- phase 2: A q3 ; stage (t+1,B_h1)
    #pragma unroll
    for (int i=0;i<2;i++){ a1_[i][0]=rdA(buf,6+i,0); a1_[i][1]=rdA(buf,6+i,1); }
    STAGE(t+1, 3);
    __builtin_amdgcn_s_barrier();
    asm volatile("s_waitcnt lgkmcnt(0)" ::: "memory");
    __builtin_amdgcn_sched_barrier(0);
    __builtin_amdgcn_s_setprio(1);
    #pragma unroll
    for (int i=0;i<2;i++)
      #pragma unroll
      for (int nj=0;nj<4;nj++){
        acc[4+i][nj] = MFMA16(a0_[i][0], bf_[nj][0], acc[4+i][nj]);
        acc[4+i][nj] = MFMA16(a0_[i][1], bf_[nj][1], acc[4+i][nj]);
      }
    __builtin_amdgcn_s_setprio(0);
    __builtin_amdgcn_s_barrier();
    // ---- phase 3: stage (t+2,A_h0); counted vmcnt with boundary drain
    STAGE(t+2, 0);
    if (t < NT-2){
      asm volatile("s_waitcnt vmcnt(2)" ::: "memory");   // leaves only t+2:A_h0 in flight
    } else {
      asm volatile("s_waitcnt vmcnt(0)" ::: "memory");   // boundary: drain
    }
    __builtin_amdgcn_s_barrier();
    __builtin_amdgcn_s_setprio(1);
    #pragma unroll
    for (int i=0;i<2;i++)
      #pragma unroll
      for (int nj=0;nj<4;nj++){
        acc[6+i][nj] = MFMA16(a1_[i][0], bf_[nj][0], acc[6+i][nj]);
        acc[6+i][nj] = MFMA16(a1_[i][1], bf_[nj][1], acc[6+i][nj]);
      }
    __builtin_amdgcn_s_setprio(0);
    __builtin_amdgcn_s_barrier();
  }

  // ---- epilogue: acc -> LDS (256x256 bf16 = 128KB, LDS is dead now) -> coalesced stores
  int er = lo*4;
  #pragma unroll
  for (int nj=0;nj<4;nj++){
    int col = wc*64 + nj*16 + lr;
    float bv = bias ? bias[n0 + col] : 0.f;
    #pragma unroll
    for (int mi=0;mi<8;mi++){
      int rowb = wr*128 + mi*16 + er;
      #pragma unroll
      for (int e=0;e<4;e++)
        lds[(rowb+e)*256 + col] = f2b(acc[mi][nj][e] + bv);
    }
  }
  asm volatile("s_waitcnt lgkmcnt(0)" ::: "memory");   // ds_writes visible cross-wave
  __builtin_amdgcn_s_barrier();
  #pragma unroll
  for (int it=0; it<8; ++it){
    int eps = it*8192 + tid*16;          // element index; 512 thr x 16 elems
    int row = eps >> 8, colb = eps & 255;
    uint4 v0 = *reinterpret_cast<const uint4*>(&lds[eps]);
    uint4 v1 = *reinterpret_cast<const uint4*>(&lds[eps + 8]);
    unsigned short* dst = C + (size_t)(m0 + row)*N + n0 + colb;
    *reinterpret_cast<uint4*>(dst)     = v0;
    *reinterpret_cast<uint4*>(dst + 8) = v1;
  }
}

// ---------- LN over 768, + pe, IN-PLACE on xe (bf16). grid (392, B), block 256.
__global__ __launch_bounds__(256) void ln1_kernel(unsigned short* __restrict__ xe,
    const float* __restrict__ g, const float* __restrict__ be, const float* __restrict__ pet){
  int b = blockIdx.y;
  int o0 = blockIdx.x*8;
  int t = threadIdx.x;
  int lane = t & 63, wv = t >> 6;
  __shared__ float ws1[8][4], ws2[8][4];
  __shared__ float mArr[8], rArr[8];
  float vals[8][3];
  #pragma unroll
  for (int oi=0;oi<8;oi++){
    size_t base = ((size_t)b*3136 + o0 + oi)*768;
    #pragma unroll
    for (int j=0;j<3;j++) vals[oi][j] = b2f(xe[base + t + 256*j]);
  }
  #pragma unroll
  for (int oi=0;oi<8;oi++){
    float s1=0.f, s2=0.f;
    #pragma unroll
    for (int j=0;j<3;j++){ float v=vals[oi][j]; s1+=v; s2+=v*v; }
    #pragma unroll
    for (int d=32; d>0; d>>=1){ s1 += __shfl_xor(s1,d); s2 += __shfl_xor(s2,d); }
    if (lane==0){ ws1[oi][wv]=s1; ws2[oi][wv]=s2; }
  }
  __syncthreads();
  if (t < 8){
    float a = ws1[t][0]+ws1[t][1]+ws1[t][2]+ws1[t][3];
    float c = ws2[t][0]+ws2[t][1]+ws2[t][2]+ws2[t][3];
    float m = a*(1.f/768.f);
    float var = c*(1.f/768.f) - m*m;
    mArr[t] = m; rArr[t] = rsqrtf(var + LN_EPS);
  }
  __syncthreads();
  #pragma unroll
  for (int oi=0;oi<8;oi++){
    size_t base = ((size_t)b*3136 + o0 + oi)*768;
    size_t pb = (size_t)(o0+oi)*768;
    float m=mArr[oi], r=rArr[oi];
    #pragma unroll
    for (int j=0;j<3;j++){
      int d = t + 256*j;
      xe[base+d] = f2b((vals[oi][j]-m)*r*g[d] + be[d] + pet[pb+d]);
    }
  }
}

// ---------- y (B,512,3136) f32 -> ny (B,3136,512) bf16 AND nyT (B,512,3136) bf16.
__global__ __launch_bounds__(256) void ln2_kernel(const float* __restrict__ y,
    unsigned short* __restrict__ ny, unsigned short* __restrict__ nyT,
    const float* __restrict__ g, const float* __restrict__ bb, const float* __restrict__ pe){
  int b = blockIdx.y;
  int o0 = blockIdx.x*32;
  int t = threadIdx.x;
  int oi = t & 31, cg = t >> 5;
  __shared__ float red1[8][33], red2[8][33];
  __shared__ float mArr[32], rArr[32];
  __shared__ unsigned short tile[32][520];
  size_t ybase = (size_t)b*512*3136 + o0;
  float vals[64];
  float s1=0.f, s2=0.f;
  #pragma unroll
  for (int ci=0; ci<64; ci++){
    int c = cg*64 + ci;
    float v = y[ybase + (size_t)c*3136 + oi];
    vals[ci] = v;
    s1 += v; s2 += v*v;
  }
  red1[cg][oi]=s1; red2[cg][oi]=s2;
  __syncthreads();
  if (t < 32){
    float a=0.f, c2=0.f;
    #pragma unroll
    for (int kk=0;kk<8;kk++){ a+=red1[kk][t]; c2+=red2[kk][t]; }
    float m=a*(1.f/512.f);
    float var=c2*(1.f/512.f)-m*m;
    mArr[t]=m; rArr[t]=rsqrtf(var+LN_EPS);
  }
  __syncthreads();
  float m = mArr[oi], r = rArr[oi];
  #pragma unroll
  for (int ci=0; ci<64; ci++){
    int c = cg*64 + ci;
    float v = (vals[ci]-m)*r*g[c] + bb[c] + pe[(size_t)c*3136 + o0 + oi];
    tile[oi][c] = f2b(v);
  }
  __syncthreads();
  size_t nybase = ((size_t)b*3136 + o0)*512;
  for (int p = t; p < 32*64; p += 256){
    int oo = p >> 6, cp = (p & 63)*8;
    *reinterpret_cast<uint4*>(ny + nybase + (size_t)oo*512 + cp) =
        *reinterpret_cast<const uint4*>(&tile[oo][cp]);
  }
  for (int c2 = t; c2 < 512; c2 += 256){
    unsigned short row[32];
    #pragma unroll
    for (int o=0;o<32;o++) row[o] = tile[o][c2];
    size_t a = ((size_t)b*512 + c2)*3136 + o0;
    #pragma unroll
    for (int u=0;u<4;u++)
      *reinterpret_cast<uint4*>(nyT + a + u*8) = *reinterpret_cast<const uint4*>(&row[u*8]);
  }
}

// ---------- fused attention, 8 waves (k-split QK^T), XCD b-chunked 1D grid 896.
__global__ __launch_bounds__(512) void attn_kernel(const unsigned short* __restrict__ q,
    const unsigned short* __restrict__ k, const unsigned short* __restrict__ vT,
    const float* __restrict__ y, float* __restrict__ outp){
  int id = blockIdx.x;
  int sid = (id & 7)*112 + (id >> 3);     // bijective: 8 XCDs x 112 blocks
  int b = sid / 56, h = sid - b*56;
  int tid = threadIdx.x;
  int lane = tid & 63, w = tid >> 6;      // 8 waves
  int wc = w & 3, wk = w >> 2;            // col quadrant, k half
  size_t base = (size_t)b*3136 + (size_t)h*56;
  __shared__ __align__(16) float SfP[2][56][60];     // partial scores (per k-half)
  __shared__ __align__(16) unsigned short Sb[64*64]; // P bf16, XOR-swizzled rows

  // ---- Phase A: partial S[:, 16wc..16wc+15] over k-half wk (8 steps of 32)
  f32x4 acc[4];
  #pragma unroll
  for (int mi=0;mi<4;mi++) acc[mi]=(f32x4){0.f,0.f,0.f,0.f};
  int lr = lane & 15, lo = lane >> 4;
  int lk = lo*8;
  int kr = wc*16 + lr; if (kr > 55) kr = 55;
  const unsigned short* krow = k + (base + kr)*512 + wk*256;
  const unsigned short* qrow = q + base*512 + wk*256;
  #pragma unroll
  for (int k0=0;k0<256;k0+=32){
    bf16x8 kf = *reinterpret_cast<const bf16x8*>(krow + k0 + lk);
    #pragma unroll
    for (int mi=0;mi<4;mi++){
      int qr = mi*16 + lr; if (qr > 55) qr = 55;
      bf16x8 qf = *reinterpret_cast<const bf16x8*>(qrow + (size_t)qr*512 + k0 + lk);
      acc[mi] = __builtin_amdgcn_mfma_f32_16x16x32_bf16(qf, kf, acc[mi], 0,0,0);
    }
  }

  // ---- T14: prefetch V^T fragments (wave owns d in [w*64, w*64+64), 2 half-passes of 32)
  const unsigned short* vb = vT + (size_t)b*512*3136 + (size_t)h*56;
  bf16x8 vfr[2][2][2];   // [hp][kt][mi]
  #pragma unroll
  for (int hp=0; hp<2; ++hp)
    #pragma unroll
    for (int kt=0;kt<2;++kt)
      #pragma unroll
      for (int mi=0;mi<2;++mi){
        int d = w*64 + hp*32 + mi*16 + lr;
        vfr[hp][kt][mi] = *reinterpret_cast<const bf16x8*>(vb + (size_t)d*3136 + kt*32 + lk);
      }

  // write partial S (raw, scale applied at combine)
  int col = wc*16 + lr;
  int er = lo*4;
  if (col < 56){
    #pragma unroll
    for (int mi=0;mi<4;mi++)
      #pragma unroll
      for (int e=0;e<4;e++){
        int row = mi*16 + er + e;
        if (row < 56) SfP[wk][row][col] = acc[mi][e];
      }
  }
  __syncthreads();

  // ---- Phase B: softmax rows 7w..7w+6 on combined partials; write P bf16 swizzled
  const float scale = 0.04419417382415922f;   // 1/sqrt(512)
  for (int r=0;r<7;r++){
    int i = w*7 + r;
    float xv = (lane<56) ? (SfP[0][i][lane] + SfP[1][i][lane])*scale : -1e30f;
    float mx = xv;
    #pragma unroll
    for (int d=32; d>0; d>>=1) mx = fmaxf(mx, __shfl_xor(mx,d));
    float ev = (lane<56) ? __expf(xv-mx) : 0.f;
    float sm = ev;
    #pragma unroll
    for (int d=32; d>0; d>>=1) sm += __shfl_xor(sm,d);
    unsigned short pv = (lane<56) ? f2b(ev/sm) : (unsigned short)0;
    int bo = i*128 + ((lane*2) ^ ((i&7)<<4));
    *reinterpret_cast<unsigned short*>(reinterpret_cast<char*>(Sb) + bo) = pv;
  }
  __syncthreads();

  // ---- P fragments (B-operand): row = query r, K = j
  bf16x8 pf[2][4];
  #pragma unroll
  for (int kt=0;kt<2;++kt)
    #pragma unroll
    for (int nj=0;nj<4;++nj){
      int row = nj*16 + lr;
      int bo = row*128 + (((kt*64) + lo*16) ^ ((row&7)<<4));
      pf[kt][nj] = *reinterpret_cast<const bf16x8*>(reinterpret_cast<const char*>(Sb) + bo);
    }

  // ---- Phase C: O^T in 2 half-passes of 32 d; store D + y directly
  #pragma unroll
  for (int hp=0; hp<2; ++hp){
    f32x4 a2[2][4];
    #pragma unroll
    for (int mi=0;mi<2;mi++)
      #pragma unroll
      for (int nj=0;nj<4;nj++) a2[mi][nj]=(f32x4){0.f,0.f,0.f,0.f};
    #pragma unroll
    for (int kt=0;kt<2;++kt)
      #pragma unroll
      for (int mi=0;mi<2;++mi)
        #pragma unroll
        for (int nj=0;nj<4;++nj)
          a2[mi][nj] = __builtin_amdgcn_mfma_f32_16x16x32_bf16(vfr[hp][kt][mi], pf[kt][nj], a2[mi][nj], 0,0,0);
    #pragma unroll
    for (int mi=0;mi<2;++mi)
      #pragma unroll
      for (int e=0;e<4;++e){
        size_t rowb = ((size_t)b*512 + w*64 + hp*32 + mi*16 + er + e)*3136 + (size_t)h*56;
        #pragma unroll
        for (int nj=0;nj<4;++nj){
          int r = nj*16 + lr;
          if (r < 56) outp[rowb + r] = a2[mi][nj][e] + y[rowb + r];
        }
      }
  }
}

extern "C" void kernel_launch(void* const* d_in, const int* in_sizes, int n_in,
                              void* d_out, int out_size, void* d_ws, size_t ws_size,
                              hipStream_t stream){
  const float* x   = (const float*)d_in[0];
  const float* y   = (const float*)d_in[1];
  const float* Wc  = (const float*)d_in[2];
  // d_in[3] = b_conv1: cancelled by the following LayerNorm -> skipped
  const float* g1  = (const float*)d_in[4];
  const float* be1 = (const float*)d_in[5];
  const float* g2  = (const float*)d_in[6];
  const float* be2 = (const float*)d_in[7];
  const float* peW = (const float*)d_in[8];
  const float* peS = (const float*)d_in[9];
  const float* Wq  = (const float*)d_in[10];
  const float* bq  = (const float*)d_in[11];
  const float* Wk  = (const float*)d_in[12];
  const float* bk  = (const float*)d_in[13];
  float* outp = (float*)d_out;

  char* p = (char*)d_ws;
  auto alloc = [&](size_t bytes)->char*{ char* r = p; p += (bytes + 255) & ~(size_t)255; return r; };
  unsigned short* WcB = (unsigned short*)alloc((size_t)3200*160*2);
  unsigned short* xt  = (unsigned short*)alloc((size_t)16*768*160*2);
  unsigned short* WqB = (unsigned short*)alloc((size_t)512*768*2);
  unsigned short* WkB = (unsigned short*)alloc((size_t)512*512*2);
  float* peWt = (float*)alloc((size_t)3136*768*4);
  unsigned short* xe  = (unsigned short*)alloc((size_t)16*3136*768*2);
  unsigned short* ny  = (unsigned short*)alloc((size_t)16*3136*512*2);
  unsigned short* nyT = (unsigned short*)alloc((size_t)16*512*3136*2 + 256);
  unsigned short* qb  = (unsigned short*)alloc((size_t)16*3136*512*2);
  unsigned short* kb  = (unsigned short*)alloc((size_t)16*3136*512*2);

  pack_weights<<<dim3((1167360+255)/256), 256, 0, stream>>>(Wc, Wq, Wk, WcB, WqB, WkB);
  pack_xt<<<dim3(24,5,16), 256, 0, stream>>>(x, xt);
  transpose_pe<<<dim3(98,24), 256, 0, stream>>>(peW, peWt, 768);

  // conv1d k=1: xe[b,o,d] = sum_l Wc[o,l]*x[b,l,d]  (single-shot K=160)
  conv160<<<dim3(25,6,16), 256, 0, stream>>>(WcB, xt, xe, 3136, 768,
                                             768LL*160LL, 3136LL*768LL);
  ln1_kernel<<<dim3(392,16), 256, 0, stream>>>(xe, g1, be1, peWt);
  ln2_kernel<<<dim3(98,16), 256, 0, stream>>>(y, ny, nyT, g2, be2, peS);
  // merged Q+K projections (8-phase BK=64, counted vmcnt, parity interleave, LDS epilogue)
  gemm256_dual<<<dim3(784), 512, 0, stream>>>(xe, WqB, qb, bq, 768,
                                              ny, WkB, kb, bk, 512, 50176, 512);
  // fused attention + residual -> d_out (8-wave k-split, O^T direct, XCD b-chunked)
  attn_kernel<<<dim3(896), 512, 0, stream>>>(qb, kb, nyT, y, outp);
}

// Round 21
// 359.012 us; speedup vs baseline: 1.0168x; 1.0168x over previous
//
#include <hip/hip_runtime.h>
#include <hip/hip_bf16.h>
#include <math.h>

typedef short bf16x8 __attribute__((ext_vector_type(8)));
typedef float f32x4 __attribute__((ext_vector_type(4)));

#define LN_EPS 1e-5f

static __device__ __forceinline__ float b2f(unsigned short u){
  unsigned int x = ((unsigned int)u) << 16; float f; __builtin_memcpy(&f,&x,4); return f;
}
static __device__ __forceinline__ unsigned short f2b(float f){
  unsigned int x; __builtin_memcpy(&x,&f,4);
  x += 0x7fffu + ((x>>16)&1u);   // RNE
  return (unsigned short)(x>>16);
}

// async global->LDS, 16B per lane; LDS dest = uniform base + lane*16
static __device__ __forceinline__ void gload_lds16(const void* g, void* l){
  __builtin_amdgcn_global_load_lds(
      (const __attribute__((address_space(1))) unsigned int*)g,
      (__attribute__((address_space(3))) unsigned int*)l, 16, 0, 0);
}

#define MFMA16(a,b,c) __builtin_amdgcn_mfma_f32_16x16x32_bf16(a,b,c,0,0,0)

// ---------- fused weight packs: Wc (3136x149 -> 3200x160 pad) + Wq copy + Wk copy
__global__ void pack_weights(const float* __restrict__ Wc, const float* __restrict__ Wq,
                             const float* __restrict__ Wk, unsigned short* __restrict__ WcB,
                             unsigned short* __restrict__ WqB, unsigned short* __restrict__ WkB){
  int idx = blockIdx.x*256 + threadIdx.x;
  if (idx < 512000){
    int r = idx / 160, kk = idx - r*160;
    float v = (r < 3136 && kk < 149) ? Wc[(size_t)r*149 + kk] : 0.f;
    WcB[idx] = f2b(v);
  } else if (idx < 905216){
    int i = idx - 512000;
    WqB[i] = f2b(Wq[i]);
  } else if (idx < 1167360){
    int i = idx - 905216;
    WkB[i] = f2b(Wk[i]);
  }
}

// ---------- x (B,149,768) f32 -> xt (B,768,160) bf16, zero pad l>=149
__global__ __launch_bounds__(256) void pack_xt(const float* __restrict__ x, unsigned short* __restrict__ xt){
  __shared__ float tile[32][33];
  int b = blockIdx.z;
  int l0 = blockIdx.y*32, d0 = blockIdx.x*32;
  int tl = threadIdx.x & 31, tw = threadIdx.x >> 5;
  for (int r=0;r<32;r+=8){
    int l = l0 + tw + r;
    tile[tw+r][tl] = (l<149) ? x[((size_t)b*149 + l)*768 + d0 + tl] : 0.f;
  }
  __syncthreads();
  for (int r=0;r<32;r+=8){
    int d = d0 + tw + r;
    int l = l0 + tl;
    if (l < 160) xt[((size_t)b*768 + d)*160 + l] = f2b(tile[tl][tw+r]);
  }
}

// ---------- pe (C,3136) f32 -> (3136,C) f32   (used for pe_wave only)
__global__ __launch_bounds__(256) void transpose_pe(const float* __restrict__ src, float* __restrict__ dst, int C){
  __shared__ float tile[32][33];
  int c0 = blockIdx.y*32, o0 = blockIdx.x*32;
  int tl = threadIdx.x & 31, tw = threadIdx.x >> 5;
  for (int r=0;r<32;r+=8)
    tile[tw+r][tl] = src[(size_t)(c0+tw+r)*3136 + o0 + tl];
  __syncthreads();
  for (int r=0;r<32;r+=8)
    dst[(size_t)(o0+tw+r)*C + c0 + tl] = tile[tl][tw+r];
}

// ---------- conv1d GEMM, K=160 single-shot: 128x128 tile, whole K in LDS (80 KB),
// ONE barrier per block, 2 blocks/CU. C[m][n] = sum_k A[m][k]*Bt[n][k].
__global__ __launch_bounds__(256)
void conv160(const unsigned short* __restrict__ A, const unsigned short* __restrict__ Bt,
             unsigned short* __restrict__ C, int M, int N,
             long long bStride, long long cStride){
  __shared__ __align__(16) unsigned short lds[40960];  // A 128x160 + B 128x160 (81920 B)
  const int K = 160;
  int tid = threadIdx.x;
  int lane = tid & 63, wave = tid >> 6;
  int wm = (wave >> 1)*64, wn = (wave & 1)*64;
  int lr = lane & 15, lo = lane >> 4;
  int m0 = blockIdx.x*128, n0 = blockIdx.y*128;
  const unsigned short* Bb = Bt + (size_t)blockIdx.z*bStride;
  unsigned short* Cb = C + (size_t)blockIdx.z*cStride;

  #pragma unroll
  for (int i=0;i<20;i++){
    int cbase = i*256 + wave*64;           // uniform per instruction
    int tensor = (cbase >= 2560) ? 1 : 0;
    int ccb = cbase - tensor*2560;
    int cc = ccb + lane;
    int r = cc / 20, pc = cc - r*20;
    int sw = (r ^ (r >> 2)) & 3;
    int ps = pc ^ sw;                       // XOR low 2 bits only; 20 = 5 groups of 4
    const unsigned short* srcT = tensor ? (Bb + (size_t)n0*K) : (A + (size_t)m0*K);
    gload_lds16(srcT + (size_t)r*K + ps*8, lds + tensor*20480 + ccb*8);
  }
  asm volatile("s_waitcnt vmcnt(0)" ::: "memory");
  __builtin_amdgcn_s_barrier();

  f32x4 acc[4][4];
  #pragma unroll
  for (int i=0;i<4;i++)
    #pragma unroll
    for (int j=0;j<4;j++) acc[i][j]=(f32x4){0.f,0.f,0.f,0.f};
  #pragma unroll
  for (int kk=0; kk<5; ++kk){
    bf16x8 af[4], bfr[4];
    #pragma unroll
    for (int mi=0;mi<4;mi++){
      int row = wm + mi*16 + lr;
      int p = kk*4 + (lo ^ ((row ^ (row>>2)) & 3));
      af[mi] = *reinterpret_cast<const bf16x8*>(&lds[row*160 + p*8]);
    }
    #pragma unroll
    for (int nj=0;nj<4;nj++){
      int row = wn + nj*16 + lr;
      int p = kk*4 + (lo ^ ((row ^ (row>>2)) & 3));
      bfr[nj] = *reinterpret_cast<const bf16x8*>(&lds[20480 + row*160 + p*8]);
    }
    #pragma unroll
    for (int mi=0;mi<4;mi++)
      #pragma unroll
      for (int nj=0;nj<4;nj++)
        acc[mi][nj] = MFMA16(af[mi], bfr[nj], acc[mi][nj]);
  }
  int er = lo*4;
  #pragma unroll
  for (int mi=0;mi<4;mi++)
    #pragma unroll
    for (int nj=0;nj<4;nj++){
      int col = n0 + wn + nj*16 + lr;
      #pragma unroll
      for (int e=0;e<4;e++){
        int row = m0 + wm + mi*16 + er + e;
        if (row < M) Cb[(size_t)row*N + col] = f2b(acc[mi][nj][e]);
      }
    }
}

// ---------- merged Q+K 256x256 8-phase GEMM (T1..T5, fixed-boundary counted vmcnt).
// grid 784; parity interleave q_sel = sid&1. BK=64, conflict-free swizzle.
// Direct global C stores (R19-measured-best epilogue).
__global__ __launch_bounds__(512)
void gemm256_dual(const unsigned short* __restrict__ A0, const unsigned short* __restrict__ Bt0,
                  unsigned short* __restrict__ C0, const float* __restrict__ bias0, int K0,
                  const unsigned short* __restrict__ A1, const unsigned short* __restrict__ Bt1,
                  unsigned short* __restrict__ C1, const float* __restrict__ bias1, int K1,
                  int M, int N){
  __shared__ __align__(16) unsigned short lds[65536];   // 131072 B
  int tid = threadIdx.x;
  int lane = tid & 63, wave = tid >> 6;
  int wr = wave >> 2, wc = wave & 3;
  int lr = lane & 15, lo = lane >> 4;
  int cpx = gridDim.x >> 3;
  int id = blockIdx.x;
  int sid = (id & 7)*cpx + (id >> 3);     // bijective XCD swizzle over 8 x cpx
  int q_sel = sid & 1;
  int s2 = sid >> 1;
  const unsigned short* A; const unsigned short* Bt; unsigned short* C;
  const float* bias; int K;
  if (q_sel == 0){ A=A0; Bt=Bt0; C=C0; bias=bias0; K=K0; }
  else           { A=A1; Bt=Bt1; C=C1; bias=bias1; K=K1; }
  int nby = N >> 8;                       // 2
  int bx = s2 / nby, by = s2 - bx*nby;
  int m0 = bx << 8, n0 = by << 8;
  int NT = K >> 6;

  f32x4 acc[8][4];
  #pragma unroll
  for (int i=0;i<8;i++)
    #pragma unroll
    for (int j=0;j<4;j++) acc[i][j]=(f32x4){0.f,0.f,0.f,0.f};

  auto STAGE = [&](int t, int h){   // h: 0=A_h0, 1=A_h1, 2=B_h0, 3=B_h1
    if (t >= NT) return;
    int buf = t & 1, tensor = h >> 1, hh = h & 1;
    int k0 = t << 6;
    unsigned short* dstbase = lds + buf*32768 + tensor*16384;
    const unsigned short* srcT = tensor ? (Bt + (size_t)n0*K) : (A + (size_t)m0*K);
    #pragma unroll
    for (int ldi=0; ldi<2; ldi++){
      int c = hh*1024 + ldi*512 + tid;
      int r = c >> 3;
      int l = (c & 7) ^ (r & 7);            // pre-swizzled source chunk
      gload_lds16(srcT + (size_t)r*K + k0 + l*8,
                  dstbase + (hh*1024 + ldi*512 + (wave<<6))*8);
    }
  };
  const char* ldsc = reinterpret_cast<const char*>(lds);
  int swz = lr & 7;
  auto rdA = [&](int buf, int mi, int kk)->bf16x8{
    int off = buf*65536 + (wr*128 + mi*16 + lr)*128 + (((kk*4+lo) ^ swz)*16);
    return *reinterpret_cast<const bf16x8*>(ldsc + off);
  };
  auto rdB = [&](int buf, int nj, int kk)->bf16x8{
    int off = buf*65536 + 32768 + (wc*64 + nj*16 + lr)*128 + (((kk*4+lo) ^ swz)*16);
    return *reinterpret_cast<const bf16x8*>(ldsc + off);
  };

  // prologue: tile0 fully + tile1 first half-tile; wait all but tile1:A_h0
  STAGE(0,0); STAGE(0,1); STAGE(0,2); STAGE(0,3); STAGE(1,0);
  asm volatile("s_waitcnt vmcnt(2)" ::: "memory");
  __builtin_amdgcn_s_barrier();

  for (int t=0; t<NT; ++t){
    int buf = t & 1;
    bf16x8 bf_[4][2], a0_[2][2], a1_[2][2];
    // ---- phase 0: B all + A q0,q1 ; stage (t+1,A_h1)
    #pragma unroll
    for (int nj=0;nj<4;nj++){ bf_[nj][0]=rdB(buf,nj,0); bf_[nj][1]=rdB(buf,nj,1); }
    #pragma unroll
    for (int i=0;i<2;i++){ a0_[i][0]=rdA(buf,i,0);   a0_[i][1]=rdA(buf,i,1); }
    #pragma unroll
    for (int i=0;i<2;i++){ a1_[i][0]=rdA(buf,2+i,0); a1_[i][1]=rdA(buf,2+i,1); }
    STAGE(t+1, 1);
    __builtin_amdgcn_s_barrier();
    asm volatile("s_waitcnt lgkmcnt(0)" ::: "memory");
    __builtin_amdgcn_sched_barrier(0);
    __builtin_amdgcn_s_setprio(1);
    #pragma unroll
    for (int i=0;i<2;i++)
      #pragma unroll
      for (int nj=0;nj<4;nj++){
        acc[i][nj] = MFMA16(a0_[i][0], bf_[nj][0], acc[i][nj]);
        acc[i][nj] = MFMA16(a0_[i][1], bf_[nj][1], acc[i][nj]);
      }
    __builtin_amdgcn_s_setprio(0);
    __builtin_amdgcn_s_barrier();
    // ---- phase 1: A q2 ; stage (t+1,B_h0)
    #pragma unroll
    for (int i=0;i<2;i++){ a0_[i][0]=rdA(buf,4+i,0); a0_[i][1]=rdA(buf,4+i,1); }
    STAGE(t+1, 2);
    __builtin_amdgcn_s_barrier();
    asm volatile("s_waitcnt lgkmcnt(0)" ::: "memory");
    __builtin_amdgcn_sched_barrier(0);
    __builtin_amdgcn_s_setprio(1);
    #pragma unroll
    for (int i=0;i<2;i++)
      #pragma unroll
      for (int nj=0;nj<4;nj++){
        acc[2+i][nj] = MFMA16(a1_[i][0], bf_[nj][0], acc[2+i][nj]);
        acc[2+i][nj] = MFMA16(a1_[i][1], bf_[nj][1], acc[2+i][nj]);
      }
    __builtin_amdgcn_s_setprio(0);
    __builtin_amdgcn_s_barrier();
    // ---- phase 2: A q3 ; stage (t+1,B_h1)
    #pragma unroll
    for (int i=0;i<2;i++){ a1_[i][0]=rdA(buf,6+i,0); a1_[i][1]=rdA(buf,6+i,1); }
    STAGE(t+1, 3);
    __builtin_amdgcn_s_barrier();
    asm volatile("s_waitcnt lgkmcnt(0)" ::: "memory");
    __builtin_amdgcn_sched_barrier(0);
    __builtin_amdgcn_s_setprio(1);
    #pragma unroll
    for (int i=0;i<2;i++)
      #pragma unroll
      for (int nj=0;nj<4;nj++){
        acc[4+i][nj] = MFMA16(a0_[i][0], bf_[nj][0], acc[4+i][nj]);
        acc[4+i][nj] = MFMA16(a0_[i][1], bf_[nj][1], acc[4+i][nj]);
      }
    __builtin_amdgcn_s_setprio(0);
    __builtin_amdgcn_s_barrier();
    // ---- phase 3: stage (t+2,A_h0); counted vmcnt with boundary drain
    STAGE(t+2, 0);
    if (t < NT-2){
      asm volatile("s_waitcnt vmcnt(2)" ::: "memory");   // leaves only t+2:A_h0 in flight
    } else {
      asm volatile("s_waitcnt vmcnt(0)" ::: "memory");   // boundary: drain
    }
    __builtin_amdgcn_s_barrier();
    __builtin_amdgcn_s_setprio(1);
    #pragma unroll
    for (int i=0;i<2;i++)
      #pragma unroll
      for (int nj=0;nj<4;nj++){
        acc[6+i][nj] = MFMA16(a1_[i][0], bf_[nj][0], acc[6+i][nj]);
        acc[6+i][nj] = MFMA16(a1_[i][1], bf_[nj][1], acc[6+i][nj]);
      }
    __builtin_amdgcn_s_setprio(0);
    __builtin_amdgcn_s_barrier();
  }

  int er = lo*4;
  #pragma unroll
  for (int nj=0;nj<4;nj++){
    int col = n0 + wc*64 + nj*16 + lr;
    float bv = bias ? bias[col] : 0.f;
    #pragma unroll
    for (int mi=0;mi<8;mi++){
      int row = m0 + wr*128 + mi*16 + er;
      #pragma unroll
      for (int e=0;e<4;e++)
        C[(size_t)(row+e)*N + col] = f2b(acc[mi][nj][e] + bv);
    }
  }
}

// ---------- LN over 768, + pe, IN-PLACE on xe (bf16). grid (392, B), block 256.
__global__ __launch_bounds__(256) void ln1_kernel(unsigned short* __restrict__ xe,
    const float* __restrict__ g, const float* __restrict__ be, const float* __restrict__ pet){
  int b = blockIdx.y;
  int o0 = blockIdx.x*8;
  int t = threadIdx.x;
  int lane = t & 63, wv = t >> 6;
  __shared__ float ws1[8][4], ws2[8][4];
  __shared__ float mArr[8], rArr[8];
  float vals[8][3];
  #pragma unroll
  for (int oi=0;oi<8;oi++){
    size_t base = ((size_t)b*3136 + o0 + oi)*768;
    #pragma unroll
    for (int j=0;j<3;j++) vals[oi][j] = b2f(xe[base + t + 256*j]);
  }
  #pragma unroll
  for (int oi=0;oi<8;oi++){
    float s1=0.f, s2=0.f;
    #pragma unroll
    for (int j=0;j<3;j++){ float v=vals[oi][j]; s1+=v; s2+=v*v; }
    #pragma unroll
    for (int d=32; d>0; d>>=1){ s1 += __shfl_xor(s1,d); s2 += __shfl_xor(s2,d); }
    if (lane==0){ ws1[oi][wv]=s1; ws2[oi][wv]=s2; }
  }
  __syncthreads();
  if (t < 8){
    float a = ws1[t][0]+ws1[t][1]+ws1[t][2]+ws1[t][3];
    float c = ws2[t][0]+ws2[t][1]+ws2[t][2]+ws2[t][3];
    float m = a*(1.f/768.f);
    float var = c*(1.f/768.f) - m*m;
    mArr[t] = m; rArr[t] = rsqrtf(var + LN_EPS);
  }
  __syncthreads();
  #pragma unroll
  for (int oi=0;oi<8;oi++){
    size_t base = ((size_t)b*3136 + o0 + oi)*768;
    size_t pb = (size_t)(o0+oi)*768;
    float m=mArr[oi], r=rArr[oi];
    #pragma unroll
    for (int j=0;j<3;j++){
      int d = t + 256*j;
      xe[base+d] = f2b((vals[oi][j]-m)*r*g[d] + be[d] + pet[pb+d]);
    }
  }
}

// ---------- y (B,512,3136) f32 -> ny (B,3136,512) bf16 AND nyT (B,512,3136) bf16.
__global__ __launch_bounds__(256) void ln2_kernel(const float* __restrict__ y,
    unsigned short* __restrict__ ny, unsigned short* __restrict__ nyT,
    const float* __restrict__ g, const float* __restrict__ bb, const float* __restrict__ pe){
  int b = blockIdx.y;
  int o0 = blockIdx.x*32;
  int t = threadIdx.x;
  int oi = t & 31, cg = t >> 5;
  __shared__ float red1[8][33], red2[8][33];
  __shared__ float mArr[32], rArr[32];
  __shared__ unsigned short tile[32][520];
  size_t ybase = (size_t)b*512*3136 + o0;
  float vals[64];
  float s1=0.f, s2=0.f;
  #pragma unroll
  for (int ci=0; ci<64; ci++){
    int c = cg*64 + ci;
    float v = y[ybase + (size_t)c*3136 + oi];
    vals[ci] = v;
    s1 += v; s2 += v*v;
  }
  red1[cg][oi]=s1; red2[cg][oi]=s2;
  __syncthreads();
  if (t < 32){
    float a=0.f, c2=0.f;
    #pragma unroll
    for (int kk=0;kk<8;kk++){ a+=red1[kk][t]; c2+=red2[kk][t]; }
    float m=a*(1.f/512.f);
    float var=c2*(1.f/512.f)-m*m;
    mArr[t]=m; rArr[t]=rsqrtf(var+LN_EPS);
  }
  __syncthreads();
  float m = mArr[oi], r = rArr[oi];
  #pragma unroll
  for (int ci=0; ci<64; ci++){
    int c = cg*64 + ci;
    float v = (vals[ci]-m)*r*g[c] + bb[c] + pe[(size_t)c*3136 + o0 + oi];
    tile[oi][c] = f2b(v);
  }
  __syncthreads();
  size_t nybase = ((size_t)b*3136 + o0)*512;
  for (int p = t; p < 32*64; p += 256){
    int oo = p >> 6, cp = (p & 63)*8;
    *reinterpret_cast<uint4*>(ny + nybase + (size_t)oo*512 + cp) =
        *reinterpret_cast<const uint4*>(&tile[oo][cp]);
  }
  for (int c2 = t; c2 < 512; c2 += 256){
    unsigned short row[32];
    #pragma unroll
    for (int o=0;o<32;o++) row[o] = tile[o][c2];
    size_t a = ((size_t)b*512 + c2)*3136 + o0;
    #pragma unroll
    for (int u=0;u<4;u++)
      *reinterpret_cast<uint4*>(nyT + a + u*8) = *reinterpret_cast<const uint4*>(&row[u*8]);
  }
}

// ---------- fused attention, 8 waves (k-split QK^T), XCD b-chunked 1D grid 896.
__global__ __launch_bounds__(512) void attn_kernel(const unsigned short* __restrict__ q,
    const unsigned short* __restrict__ k, const unsigned short* __restrict__ vT,
    const float* __restrict__ y, float* __restrict__ outp){
  int id = blockIdx.x;
  int sid = (id & 7)*112 + (id >> 3);     // bijective: 8 XCDs x 112 blocks
  int b = sid / 56, h = sid - b*56;
  int tid = threadIdx.x;
  int lane = tid & 63, w = tid >> 6;      // 8 waves
  int wc = w & 3, wk = w >> 2;            // col quadrant, k half
  size_t base = (size_t)b*3136 + (size_t)h*56;
  __shared__ __align__(16) float SfP[2][56][60];     // partial scores (per k-half)
  __shared__ __align__(16) unsigned short Sb[64*64]; // P bf16, XOR-swizzled rows

  // ---- Phase A: partial S[:, 16wc..16wc+15] over k-half wk (8 steps of 32)
  f32x4 acc[4];
  #pragma unroll
  for (int mi=0;mi<4;mi++) acc[mi]=(f32x4){0.f,0.f,0.f,0.f};
  int lr = lane & 15, lo = lane >> 4;
  int lk = lo*8;
  int kr = wc*16 + lr; if (kr > 55) kr = 55;
  const unsigned short* krow = k + (base + kr)*512 + wk*256;
  const unsigned short* qrow = q + base*512 + wk*256;
  #pragma unroll
  for (int k0=0;k0<256;k0+=32){
    bf16x8 kf = *reinterpret_cast<const bf16x8*>(krow + k0 + lk);
    #pragma unroll
    for (int mi=0;mi<4;mi++){
      int qr = mi*16 + lr; if (qr > 55) qr = 55;
      bf16x8 qf = *reinterpret_cast<const bf16x8*>(qrow + (size_t)qr*512 + k0 + lk);
      acc[mi] = __builtin_amdgcn_mfma_f32_16x16x32_bf16(qf, kf, acc[mi], 0,0,0);
    }
  }

  // ---- T14: prefetch V^T fragments (wave owns d in [w*64, w*64+64), 2 half-passes of 32)
  const unsigned short* vb = vT + (size_t)b*512*3136 + (size_t)h*56;
  bf16x8 vfr[2][2][2];   // [hp][kt][mi]
  #pragma unroll
  for (int hp=0; hp<2; ++hp)
    #pragma unroll
    for (int kt=0;kt<2;++kt)
      #pragma unroll
      for (int mi=0;mi<2;++mi){
        int d = w*64 + hp*32 + mi*16 + lr;
        vfr[hp][kt][mi] = *reinterpret_cast<const bf16x8*>(vb + (size_t)d*3136 + kt*32 + lk);
      }

  // write partial S (raw, scale applied at combine)
  int col = wc*16 + lr;
  int er = lo*4;
  if (col < 56){
    #pragma unroll
    for (int mi=0;mi<4;mi++)
      #pragma unroll
      for (int e=0;e<4;e++){
        int row = mi*16 + er + e;
        if (row < 56) SfP[wk][row][col] = acc[mi][e];
      }
  }
  __syncthreads();

  // ---- Phase B: softmax rows 7w..7w+6 on combined partials; write P bf16 swizzled
  const float scale = 0.04419417382415922f;   // 1/sqrt(512)
  for (int r=0;r<7;r++){
    int i = w*7 + r;
    float xv = (lane<56) ? (SfP[0][i][lane] + SfP[1][i][lane])*scale : -1e30f;
    float mx = xv;
    #pragma unroll
    for (int d=32; d>0; d>>=1) mx = fmaxf(mx, __shfl_xor(mx,d));
    float ev = (lane<56) ? __expf(xv-mx) : 0.f;
    float sm = ev;
    #pragma unroll
    for (int d=32; d>0; d>>=1) sm += __shfl_xor(sm,d);
    unsigned short pv = (lane<56) ? f2b(ev/sm) : (unsigned short)0;
    int bo = i*128 + ((lane*2) ^ ((i&7)<<4));
    *reinterpret_cast<unsigned short*>(reinterpret_cast<char*>(Sb) + bo) = pv;
  }
  __syncthreads();

  // ---- P fragments (B-operand): row = query r, K = j
  bf16x8 pf[2][4];
  #pragma unroll
  for (int kt=0;kt<2;++kt)
    #pragma unroll
    for (int nj=0;nj<4;++nj){
      int row = nj*16 + lr;
      int bo = row*128 + (((kt*64) + lo*16) ^ ((row&7)<<4));
      pf[kt][nj] = *reinterpret_cast<const bf16x8*>(reinterpret_cast<const char*>(Sb) + bo);
    }

  // ---- Phase C: O^T in 2 half-passes of 32 d; store D + y directly
  #pragma unroll
  for (int hp=0; hp<2; ++hp){
    f32x4 a2[2][4];
    #pragma unroll
    for (int mi=0;mi<2;mi++)
      #pragma unroll
      for (int nj=0;nj<4;nj++) a2[mi][nj]=(f32x4){0.f,0.f,0.f,0.f};
    #pragma unroll
    for (int kt=0;kt<2;++kt)
      #pragma unroll
      for (int mi=0;mi<2;++mi)
        #pragma unroll
        for (int nj=0;nj<4;++nj)
          a2[mi][nj] = __builtin_amdgcn_mfma_f32_16x16x32_bf16(vfr[hp][kt][mi], pf[kt][nj], a2[mi][nj], 0,0,0);
    #pragma unroll
    for (int mi=0;mi<2;++mi)
      #pragma unroll
      for (int e=0;e<4;++e){
        size_t rowb = ((size_t)b*512 + w*64 + hp*32 + mi*16 + er + e)*3136 + (size_t)h*56;
        #pragma unroll
        for (int nj=0;nj<4;++nj){
          int r = nj*16 + lr;
          if (r < 56) outp[rowb + r] = a2[mi][nj][e] + y[rowb + r];
        }
      }
  }
}

extern "C" void kernel_launch(void* const* d_in, const int* in_sizes, int n_in,
                              void* d_out, int out_size, void* d_ws, size_t ws_size,
                              hipStream_t stream){
  const float* x   = (const float*)d_in[0];
  const float* y   = (const float*)d_in[1];
  const float* Wc  = (const float*)d_in[2];
  // d_in[3] = b_conv1: cancelled by the following LayerNorm -> skipped
  const float* g1  = (const float*)d_in[4];
  const float* be1 = (const float*)d_in[5];
  const float* g2  = (const float*)d_in[6];
  const float* be2 = (const float*)d_in[7];
  const float* peW = (const float*)d_in[8];
  const float* peS = (const float*)d_in[9];
  const float* Wq  = (const float*)d_in[10];
  const float* bq  = (const float*)d_in[11];
  const float* Wk  = (const float*)d_in[12];
  const float* bk  = (const float*)d_in[13];
  float* outp = (float*)d_out;

  char* p = (char*)d_ws;
  auto alloc = [&](size_t bytes)->char*{ char* r = p; p += (bytes + 255) & ~(size_t)255; return r; };
  unsigned short* WcB = (unsigned short*)alloc((size_t)3200*160*2);
  unsigned short* xt  = (unsigned short*)alloc((size_t)16*768*160*2);
  unsigned short* WqB = (unsigned short*)alloc((size_t)512*768*2);
  unsigned short* WkB = (unsigned short*)alloc((size_t)512*512*2);
  float* peWt = (float*)alloc((size_t)3136*768*4);
  unsigned short* xe  = (unsigned short*)alloc((size_t)16*3136*768*2);
  unsigned short* ny  = (unsigned short*)alloc((size_t)16*3136*512*2);
  unsigned short* nyT = (unsigned short*)alloc((size_t)16*512*3136*2 + 256);
  unsigned short* qb  = (unsigned short*)alloc((size_t)16*3136*512*2);
  unsigned short* kb  = (unsigned short*)alloc((size_t)16*3136*512*2);

  pack_weights<<<dim3((1167360+255)/256), 256, 0, stream>>>(Wc, Wq, Wk, WcB, WqB, WkB);
  pack_xt<<<dim3(24,5,16), 256, 0, stream>>>(x, xt);
  transpose_pe<<<dim3(98,24), 256, 0, stream>>>(peW, peWt, 768);

  // conv1d k=1: xe[b,o,d] = sum_l Wc[o,l]*x[b,l,d]  (single-shot K=160)
  conv160<<<dim3(25,6,16), 256, 0, stream>>>(WcB, xt, xe, 3136, 768,
                                             768LL*160LL, 3136LL*768LL);
  ln1_kernel<<<dim3(392,16), 256, 0, stream>>>(xe, g1, be1, peWt);
  ln2_kernel<<<dim3(98,16), 256, 0, stream>>>(y, ny, nyT, g2, be2, peS);
  // merged Q+K projections (8-phase BK=64, counted vmcnt, parity interleave)
  gemm256_dual<<<dim3(784), 512, 0, stream>>>(xe, WqB, qb, bq, 768,
                                              ny, WkB, kb, bk, 512, 50176, 512);
  // fused attention + residual -> d_out (8-wave k-split, O^T direct, XCD b-chunked)
  attn_kernel<<<dim3(896), 512, 0, stream>>>(qb, kb, nyT, y, outp);
}